// Round 6
// baseline (1542.050 us; speedup 1.0000x reference)
//
#include <hip/hip_runtime.h>

#define NN 12288
#define NE 6144
#define ND 256

typedef __attribute__((ext_vector_type(8))) short short8;
typedef __attribute__((ext_vector_type(4))) float f32x4;
typedef unsigned short u16;
typedef unsigned int u32;

__device__ inline u16 f2bf(float f) {
  union { float f; u32 u; } v; v.f = f;
  u32 r = v.u + 0x7fffu + ((v.u >> 16) & 1u);
  return (u16)(r >> 16);
}

__device__ inline void gll16(const void* g, void* l) {
  __builtin_amdgcn_global_load_lds(
      (const __attribute__((address_space(1))) u32*)g,
      (__attribute__((address_space(3))) u32*)l, 16, 0, 0);
}

// Stage B tile [256 n][32 k] bf16 into LDS, 256-thread (4-wave) version.
// Swizzle: global chunk c of row n lands at position (c + (n>>1)) & 3.
__device__ inline void stage_B4(const u16* __restrict__ Bg, int ldb, int k0,
                                u16* __restrict__ Blds) {
  const int w = threadIdx.x >> 6;
  const int lane = threadIdx.x & 63;
  const int dd = lane >> 2, p = lane & 3;
#pragma unroll
  for (int s = 0; s < 4; ++s) {
    const int dbase = (w * 4 + s) * 16;
    const int n = dbase + dd;
    const int c = (p - (n >> 1)) & 3;
    gll16(Bg + (size_t)n * ldb + k0 + c * 8, Blds + dbase * 32);
  }
}

// Same staging with 512 threads (8 waves): 2 gll16/thread.
__device__ inline void stage_B8(const u16* __restrict__ Bg, int ldb, int k0,
                                u16* __restrict__ Blds) {
  const int w = threadIdx.x >> 6;          // 0..7
  const int lane = threadIdx.x & 63;
  const int dd = lane >> 2, p = lane & 3;
#pragma unroll
  for (int s = 0; s < 2; ++s) {
    const int dbase = (w * 2 + s) * 16;    // covers 0..255 rows
    const int n = dbase + dd;
    const int c = (p - (n >> 1)) & 3;
    gll16(Bg + (size_t)n * ldb + k0 + c * 8, Blds + dbase * 32);
  }
}

__device__ inline short8 load_B(const u16* __restrict__ Blds, int n, int quad) {
  const int p = (quad + (n >> 1)) & 3;
  return *(const short8*)(Blds + n * 32 + p * 8);
}

// One 32-K MFMA step for a 64x64 wave tile; A rows start at arow0.
__device__ inline void compute_tile(const u16* __restrict__ Al, int arow0,
                                    const u16* __restrict__ Bl, int bcol0,
                                    int ln, int quad, f32x4 (&acc)[4][4]) {
  short8 af[4];
#pragma unroll
  for (int mt = 0; mt < 4; ++mt)
    af[mt] = *(const short8*)(Al + (arow0 + mt * 16 + ln) * 40 + quad * 8);
#pragma unroll
  for (int nt = 0; nt < 4; ++nt) {
    short8 bf = load_B(Bl, bcol0 + nt * 16 + ln, quad);
#pragma unroll
    for (int mt = 0; mt < 4; ++mt)
      acc[nt][mt] = __builtin_amdgcn_mfma_f32_16x16x32_bf16(af[mt], bf, acc[nt][mt], 0, 0, 0);
  }
}

__device__ inline short8 pack8(float4 f0, float4 f1) {
  short8 av;
  av[0] = (short)f2bf(f0.x); av[1] = (short)f2bf(f0.y);
  av[2] = (short)f2bf(f0.z); av[3] = (short)f2bf(f0.w);
  av[4] = (short)f2bf(f1.x); av[5] = (short)f2bf(f1.y);
  av[6] = (short)f2bf(f1.z); av[7] = (short)f2bf(f1.w);
  return av;
}

// ---------------- kernel 1: xn_t[d][v] = dv[v]*(x@W + b)  (bf16, transposed)
__global__ __launch_bounds__(256) void k_xform(
    const float* __restrict__ x, const u16* __restrict__ Wt,
    const float* __restrict__ b, const float* __restrict__ dv,
    u16* __restrict__ xnt) {
  __shared__ u16 Alds[64 * 40];
  __shared__ u16 Blds[256 * 32];
  const int tid = threadIdx.x;
  const int w = tid >> 6, lane = tid & 63, ln = lane & 15, quad = lane >> 4;
  const int m0 = blockIdx.x * 64;
  const int am = tid >> 2, ac = (tid & 3) * 8;
  f32x4 acc[4][4] = {};
  for (int kt = 0; kt < ND / 32; ++kt) {
    const int k0 = kt * 32;
    __syncthreads();
    stage_B4(Wt, ND, k0, Blds);
    const float4* pa = (const float4*)(x + (size_t)(m0 + am) * ND + k0 + ac);
    *(short8*)(Alds + am * 40 + ac) = pack8(pa[0], pa[1]);
    __syncthreads();
    compute_tile(Alds, 0, Blds, w * 64, ln, quad, acc);
  }
#pragma unroll
  for (int nt = 0; nt < 4; ++nt) {
    const int d = w * 64 + nt * 16 + ln;
    const float bb = b[d];
#pragma unroll
    for (int mt = 0; mt < 4; ++mt) {
      const int vb = m0 + mt * 16 + quad * 4;
      f32x4 a = acc[nt][mt];
      union { u16 h[4]; uint2 u; } pk;
#pragma unroll
      for (int r = 0; r < 4; ++r) pk.h[r] = f2bf(dv[vb + r] * (a[r] + bb));
      *(uint2*)(xnt + (size_t)d * NN + vb) = pk.u;
    }
  }
}

// ---------------- GEMM1 split-K: P1[chunk][e][d] = (H^T @ xn) chunk partial
// grid (48, 16), 512 threads. Block tile 128e x 256d, 8 waves of 64x64.
template <int NC>
__global__ __launch_bounds__(512) void k_gemm1s(
    const float* __restrict__ H, const u16* __restrict__ xnt,
    float* __restrict__ P1) {
  constexpr int KLEN = NN / NC;   // 768
  __shared__ u16 Alds[128 * 40];
  __shared__ u16 Blds[256 * 32];
  const int tid = threadIdx.x;
  const int w = tid >> 6, lane = tid & 63, ln = lane & 15, quad = lane >> 4;
  const int wn = w & 3, wm = w >> 2;
  const int e0 = blockIdx.x * 128;
  const int kbase = blockIdx.y * KLEN;
  const int ec = tid & 31, vp = tid >> 5;   // e-chunk-of-4, v-pair
  f32x4 acc[4][4] = {};
  for (int kt = 0; kt < KLEN / 32; ++kt) {
    const int k0 = kbase + kt * 32;
    __syncthreads();
    stage_B8(xnt, NN, k0, Blds);
    const int v = k0 + vp * 2;
    const float4 h0 = *(const float4*)(H + (size_t)v * NE + e0 + ec * 4);
    const float4 h1 = *(const float4*)(H + (size_t)(v + 1) * NE + e0 + ec * 4);
    const float a0[4] = {h0.x, h0.y, h0.z, h0.w};
    const float a1[4] = {h1.x, h1.y, h1.z, h1.w};
#pragma unroll
    for (int j = 0; j < 4; ++j) {
      u32 pk = (u32)f2bf(a0[j]) | ((u32)f2bf(a1[j]) << 16);
      *(u32*)(Alds + (ec * 4 + j) * 40 + vp * 2) = pk;
    }
    __syncthreads();
    compute_tile(Alds, wm * 64, Blds, wn * 64, ln, quad, acc);
  }
  float* P = P1 + (size_t)blockIdx.y * NE * ND;
#pragma unroll
  for (int nt = 0; nt < 4; ++nt) {
    const int d = wn * 64 + nt * 16 + ln;
#pragma unroll
    for (int mt = 0; mt < 4; ++mt) {
      const int eb = e0 + wm * 64 + mt * 16 + quad * 4;
      f32x4 a = acc[nt][mt];
#pragma unroll
      for (int r = 0; r < 4; ++r)
        P[(size_t)(eb + r) * ND + d] = a[r];
    }
  }
}

// ---------------- red1: xhet[d][e] = bf16(de[e] * sum_c P1[c][e][d])
template <int NC>
__global__ __launch_bounds__(256) void k_red1(
    const float* __restrict__ P1, const float* __restrict__ de,
    u16* __restrict__ xhet) {
  const int tid = threadIdx.x;
  const int e0 = blockIdx.x * 16;
  union { u16 h[16]; uint4 q[2]; } pk;
#pragma unroll
  for (int i = 0; i < 16; ++i) {
    float s = 0.f;
#pragma unroll
    for (int c = 0; c < NC; ++c)
      s += P1[(size_t)c * NE * ND + (size_t)(e0 + i) * ND + tid];
    pk.h[i] = f2bf(de[e0 + i] * s);
  }
  uint4* dst = (uint4*)(xhet + (size_t)tid * NE + e0);
  dst[0] = pk.q[0];
  dst[1] = pk.q[1];
}

// ---------------- GEMM2 split-K: P2[chunk][v][d] = (H @ xhe_n) chunk partial
// grid (96, 8), 512 threads. Block tile 128v x 256d, 8 waves of 64x64.
template <int NC>
__global__ __launch_bounds__(512) void k_gemm2s(
    const float* __restrict__ H, const u16* __restrict__ xhet,
    float* __restrict__ P2) {
  constexpr int KLEN = NE / NC;   // 768
  __shared__ u16 Alds[128 * 40];
  __shared__ u16 Blds[256 * 32];
  const int tid = threadIdx.x;
  const int w = tid >> 6, lane = tid & 63, ln = lane & 15, quad = lane >> 4;
  const int wn = w & 3, wm = w >> 2;
  const int m0 = blockIdx.x * 128;
  const int kbase = blockIdx.y * KLEN;
  const int am = tid >> 2, ac = (tid & 3) * 8;   // am 0..127
  f32x4 acc[4][4] = {};
  for (int kt = 0; kt < KLEN / 32; ++kt) {
    const int k0 = kbase + kt * 32;
    __syncthreads();
    stage_B8(xhet, NE, k0, Blds);
    const float4* pa = (const float4*)(H + (size_t)(m0 + am) * NE + k0 + ac);
    *(short8*)(Alds + am * 40 + ac) = pack8(pa[0], pa[1]);
    __syncthreads();
    compute_tile(Alds, wm * 64, Blds, wn * 64, ln, quad, acc);
  }
  float* P = P2 + (size_t)blockIdx.y * NN * ND;
#pragma unroll
  for (int nt = 0; nt < 4; ++nt) {
    const int d = wn * 64 + nt * 16 + ln;
#pragma unroll
    for (int mt = 0; mt < 4; ++mt) {
      const int vb = m0 + wm * 64 + mt * 16 + quad * 4;
      f32x4 a = acc[nt][mt];
#pragma unroll
      for (int r = 0; r < 4; ++r)
        P[(size_t)(vb + r) * ND + d] = a[r];
    }
  }
}

// ---------------- red2: out[v][d] = dv[v] * sum_c P2[c][v][d]
template <int NC>
__global__ __launch_bounds__(256) void k_red2(
    const float* __restrict__ P2, const float* __restrict__ dv,
    float* __restrict__ out) {
  const int tid = threadIdx.x;
  const int v0 = blockIdx.x * 16;
#pragma unroll
  for (int i = 0; i < 16; ++i) {
    float s = 0.f;
#pragma unroll
    for (int c = 0; c < NC; ++c)
      s += P2[(size_t)c * NN * ND + (size_t)(v0 + i) * ND + tid];
    out[(size_t)(v0 + i) * ND + tid] = dv[v0 + i] * s;
  }
}

// ---------------- prep: diag extraction + W transpose to bf16
__global__ __launch_bounds__(256) void k_prep(
    const float* __restrict__ W, const float* __restrict__ Dv,
    const float* __restrict__ De, u16* __restrict__ Wt,
    float* __restrict__ dv, float* __restrict__ de) {
  const int t = blockIdx.x * 256 + threadIdx.x;   // 65536 threads
  const int d = t >> 8, k = t & 255;
  Wt[d * 256 + k] = f2bf(W[k * 256 + d]);
  if (t < NN) dv[t] = Dv[(size_t)t * (NN + 1)];
  if (t < NE) de[t] = De[(size_t)t * (NE + 1)];
}

extern "C" void kernel_launch(void* const* d_in, const int* in_sizes, int n_in,
                              void* d_out, int out_size, void* d_ws, size_t ws_size,
                              hipStream_t stream) {
  const float* x  = (const float*)d_in[0];
  const float* H  = (const float*)d_in[1];
  const float* Dv = (const float*)d_in[2];
  const float* De = (const float*)d_in[3];
  const float* W  = (const float*)d_in[4];
  const float* b  = (const float*)d_in[5];
  float* out = (float*)d_out;
  char* ws = (char*)d_ws;
  u16* xnt   = (u16*)ws;                      // 256 x 12288 bf16 = 6291456 B
  u16* xhet  = (u16*)(ws + 6291456);          // 256 x 6144 bf16  = 3145728 B
  u16* Wt    = (u16*)(ws + 9437184);          // 256 x 256 bf16   = 131072 B
  float* dv  = (float*)(ws + 9568256);        // 12288 f32
  float* de  = (float*)(ws + 9617408);        // 6144 f32
  float* P1  = (float*)(ws + 9641984);        // 100663296 B, P2 aliases P1
  float* P2  = P1;

  hipLaunchKernelGGL(k_prep,       dim3(256), dim3(256), 0, stream, W, Dv, De, Wt, dv, de);
  hipLaunchKernelGGL(k_xform,      dim3(NN / 64), dim3(256), 0, stream, x, Wt, b, dv, xnt);
  // MEASUREMENT ROUND: gemm1/gemm2 launched 3x each (idempotent rewrites).
  // dur_new - dur_r5 = 2*(t_g1 + t_g2). Decision table in journal.
  hipLaunchKernelGGL(k_gemm1s<16>, dim3(NE / 128, 16), dim3(512), 0, stream, H, xnt, P1);
  hipLaunchKernelGGL(k_gemm1s<16>, dim3(NE / 128, 16), dim3(512), 0, stream, H, xnt, P1);
  hipLaunchKernelGGL(k_gemm1s<16>, dim3(NE / 128, 16), dim3(512), 0, stream, H, xnt, P1);
  hipLaunchKernelGGL(k_red1<16>,   dim3(NE / 16), dim3(256), 0, stream, P1, de, xhet);
  hipLaunchKernelGGL(k_gemm2s<8>,  dim3(NN / 128, 8), dim3(512), 0, stream, H, xhet, P2);
  hipLaunchKernelGGL(k_gemm2s<8>,  dim3(NN / 128, 8), dim3(512), 0, stream, H, xhet, P2);
  hipLaunchKernelGGL(k_gemm2s<8>,  dim3(NN / 128, 8), dim3(512), 0, stream, H, xhet, P2);
  hipLaunchKernelGGL(k_red2<8>,    dim3(NN / 16), dim3(256), 0, stream, P2, dv, out);
}

// Round 7
// 1067.763 us; speedup vs baseline: 1.4442x; 1.4442x over previous
//
#include <hip/hip_runtime.h>

#define NN 12288
#define NE 6144
#define ND 256

typedef __attribute__((ext_vector_type(8))) short short8;
typedef __attribute__((ext_vector_type(4))) float f32x4;
typedef unsigned short u16;
typedef unsigned int u32;

__device__ inline u16 f2bf(float f) {
  union { float f; u32 u; } v; v.f = f;
  u32 r = v.u + 0x7fffu + ((v.u >> 16) & 1u);
  return (u16)(r >> 16);
}

__device__ inline void gll16(const void* g, void* l) {
  __builtin_amdgcn_global_load_lds(
      (const __attribute__((address_space(1))) u32*)g,
      (__attribute__((address_space(3))) u32*)l, 16, 0, 0);
}

// Stage B tile [256 n][32 k] bf16 into LDS, 256-thread (4-wave) version.
// Swizzle: global chunk c of row n lands at position (c + (n>>1)) & 3.
__device__ inline void stage_B4(const u16* __restrict__ Bg, int ldb, int k0,
                                u16* __restrict__ Blds) {
  const int w = threadIdx.x >> 6;
  const int lane = threadIdx.x & 63;
  const int dd = lane >> 2, p = lane & 3;
#pragma unroll
  for (int s = 0; s < 4; ++s) {
    const int dbase = (w * 4 + s) * 16;
    const int n = dbase + dd;
    const int c = (p - (n >> 1)) & 3;
    gll16(Bg + (size_t)n * ldb + k0 + c * 8, Blds + dbase * 32);
  }
}

// Same staging with 512 threads (8 waves): 2 gll16/thread (vmcnt +2).
__device__ inline void stage_B8(const u16* __restrict__ Bg, int ldb, int k0,
                                u16* __restrict__ Blds) {
  const int w = threadIdx.x >> 6;          // 0..7
  const int lane = threadIdx.x & 63;
  const int dd = lane >> 2, p = lane & 3;
#pragma unroll
  for (int s = 0; s < 2; ++s) {
    const int dbase = (w * 2 + s) * 16;    // covers 0..255 rows
    const int n = dbase + dd;
    const int c = (p - (n >> 1)) & 3;
    gll16(Bg + (size_t)n * ldb + k0 + c * 8, Blds + dbase * 32);
  }
}

__device__ inline short8 load_B(const u16* __restrict__ Blds, int n, int quad) {
  const int p = (quad + (n >> 1)) & 3;
  return *(const short8*)(Blds + n * 32 + p * 8);
}

// One 32-K MFMA step for a 64x64 wave tile; A rows start at arow0.
__device__ inline void compute_tile(const u16* __restrict__ Al, int arow0,
                                    const u16* __restrict__ Bl, int bcol0,
                                    int ln, int quad, f32x4 (&acc)[4][4]) {
  short8 af[4];
#pragma unroll
  for (int mt = 0; mt < 4; ++mt)
    af[mt] = *(const short8*)(Al + (arow0 + mt * 16 + ln) * 40 + quad * 8);
#pragma unroll
  for (int nt = 0; nt < 4; ++nt) {
    short8 bf = load_B(Bl, bcol0 + nt * 16 + ln, quad);
#pragma unroll
    for (int mt = 0; mt < 4; ++mt)
      acc[nt][mt] = __builtin_amdgcn_mfma_f32_16x16x32_bf16(af[mt], bf, acc[nt][mt], 0, 0, 0);
  }
}

__device__ inline short8 pack8(float4 f0, float4 f1) {
  short8 av;
  av[0] = (short)f2bf(f0.x); av[1] = (short)f2bf(f0.y);
  av[2] = (short)f2bf(f0.z); av[3] = (short)f2bf(f0.w);
  av[4] = (short)f2bf(f1.x); av[5] = (short)f2bf(f1.y);
  av[6] = (short)f2bf(f1.z); av[7] = (short)f2bf(f1.w);
  return av;
}

// ---------------- kernel 1: xn_t[d][v] = dv[v]*(x@W + b)  (bf16, transposed)
// Verified round-0 structure (small kernel, ~5 us).
__global__ __launch_bounds__(256) void k_xform(
    const float* __restrict__ x, const u16* __restrict__ Wt,
    const float* __restrict__ b, const float* __restrict__ dv,
    u16* __restrict__ xnt) {
  __shared__ u16 Alds[64 * 40];
  __shared__ u16 Blds[256 * 32];
  const int tid = threadIdx.x;
  const int w = tid >> 6, lane = tid & 63, ln = lane & 15, quad = lane >> 4;
  const int m0 = blockIdx.x * 64;
  const int am = tid >> 2, ac = (tid & 3) * 8;
  f32x4 acc[4][4] = {};
  for (int kt = 0; kt < ND / 32; ++kt) {
    const int k0 = kt * 32;
    __syncthreads();
    stage_B4(Wt, ND, k0, Blds);
    const float4* pa = (const float4*)(x + (size_t)(m0 + am) * ND + k0 + ac);
    *(short8*)(Alds + am * 40 + ac) = pack8(pa[0], pa[1]);
    __syncthreads();
    compute_tile(Alds, 0, Blds, w * 64, ln, quad, acc);
  }
#pragma unroll
  for (int nt = 0; nt < 4; ++nt) {
    const int d = w * 64 + nt * 16 + ln;
    const float bb = b[d];
#pragma unroll
    for (int mt = 0; mt < 4; ++mt) {
      const int vb = m0 + mt * 16 + quad * 4;
      f32x4 a = acc[nt][mt];
      union { u16 h[4]; uint2 u; } pk;
#pragma unroll
      for (int r = 0; r < 4; ++r) pk.h[r] = f2bf(dv[vb + r] * (a[r] + bb));
      *(uint2*)(xnt + (size_t)d * NN + vb) = pk.u;
    }
  }
}

// ---------------- GEMM1 split-K, counted-vmcnt pipeline.
// grid (48, 16), 512 threads. Block tile 128e x 256d, 8 waves of 64x64.
// K-loop: issue A(t+1),B(t+1) -> vmcnt(4) [waits only B(t), the oldest 2]
// -> barrier -> MFMA(t) -> barrier -> ds_write A(t+1). Never drains to 0.
template <int NC>
__global__ __launch_bounds__(512) void k_gemm1s(
    const float* __restrict__ H, const u16* __restrict__ xnt,
    float* __restrict__ P1) {
  constexpr int KLEN = NN / NC;   // 768
  constexpr int NT = KLEN / 32;   // 24
  __shared__ u16 Alds[2][128 * 40];
  __shared__ u16 Blds[2][256 * 32];
  const int tid = threadIdx.x;
  const int w = tid >> 6, lane = tid & 63, ln = lane & 15, quad = lane >> 4;
  const int wn = w & 3, wm = w >> 2;
  const int e0 = blockIdx.x * 128;
  const int kbase = blockIdx.y * KLEN;
  const int ec = tid & 31, vp = tid >> 5;   // e-chunk-of-4, v-pair
  f32x4 acc[4][4] = {};
  // Per-thread A source: rows (kbase + t*32 + vp*2), (…+1); 4 floats along e.
  const float* aH = H + (size_t)(kbase + vp * 2) * NE + e0 + ec * 4;

  // ---- prologue: tile 0 staged, full drain (one-time cost)
  {
    float4 a0 = *(const float4*)(aH);
    float4 a1 = *(const float4*)(aH + NE);
    stage_B8(xnt, NN, kbase, Blds[0]);
    const float p0[4] = {a0.x, a0.y, a0.z, a0.w};
    const float p1[4] = {a1.x, a1.y, a1.z, a1.w};
#pragma unroll
    for (int j = 0; j < 4; ++j) {
      u32 pk = (u32)f2bf(p0[j]) | ((u32)f2bf(p1[j]) << 16);
      *(u32*)(Alds[0] + (ec * 4 + j) * 40 + vp * 2) = pk;
    }
    asm volatile("s_waitcnt vmcnt(0) lgkmcnt(0)" ::: "memory");
    __builtin_amdgcn_s_barrier();
    __builtin_amdgcn_sched_barrier(0);
  }
  int cur = 0;
  for (int t = 0; t < NT - 1; ++t) {
    const int nxt = cur ^ 1;
    // issue A(t+1) (regs, compiler-tracked) and B(t+1) (gll16 -> Blds[nxt])
    const float* ap = aH + (size_t)((t + 1) * 32) * NE;
    float4 ma0 = *(const float4*)(ap);
    float4 ma1 = *(const float4*)(ap + NE);
    stage_B8(xnt, NN, kbase + (t + 1) * 32, Blds[nxt]);
    // B(t) is the oldest pair in the queue -> vmcnt(4) lands exactly it.
    asm volatile("s_waitcnt vmcnt(4) lgkmcnt(0)" ::: "memory");
    __builtin_amdgcn_s_barrier();
    __builtin_amdgcn_sched_barrier(0);
    compute_tile(Alds[cur], wm * 64, Blds[cur], wn * 64, ln, quad, acc);
    __builtin_amdgcn_s_barrier();        // free cur LDS for next-iter staging
    __builtin_amdgcn_sched_barrier(0);
    // ds_write A(t+1) into freed buffer (lgkm covered at next iter's waitcnt)
    const float q0[4] = {ma0.x, ma0.y, ma0.z, ma0.w};
    const float q1[4] = {ma1.x, ma1.y, ma1.z, ma1.w};
#pragma unroll
    for (int j = 0; j < 4; ++j) {
      u32 pk = (u32)f2bf(q0[j]) | ((u32)f2bf(q1[j]) << 16);
      *(u32*)(Alds[nxt] + (ec * 4 + j) * 40 + vp * 2) = pk;
    }
    cur = nxt;
  }
  // ---- epilogue: last tile
  asm volatile("s_waitcnt vmcnt(0) lgkmcnt(0)" ::: "memory");
  __builtin_amdgcn_s_barrier();
  __builtin_amdgcn_sched_barrier(0);
  compute_tile(Alds[cur], wm * 64, Blds[cur], wn * 64, ln, quad, acc);

  float* P = P1 + (size_t)blockIdx.y * NE * ND;
#pragma unroll
  for (int nt = 0; nt < 4; ++nt) {
    const int d = wn * 64 + nt * 16 + ln;
#pragma unroll
    for (int mt = 0; mt < 4; ++mt) {
      const int eb = e0 + wm * 64 + mt * 16 + quad * 4;
      f32x4 a = acc[nt][mt];
#pragma unroll
      for (int r = 0; r < 4; ++r)
        P[(size_t)(eb + r) * ND + d] = a[r];
    }
  }
}

// ---------------- red1: xhet[d][e] = bf16(de[e] * sum_c P1[c][e][d])
template <int NC>
__global__ __launch_bounds__(256) void k_red1(
    const float* __restrict__ P1, const float* __restrict__ de,
    u16* __restrict__ xhet) {
  const int tid = threadIdx.x;
  const int e0 = blockIdx.x * 16;
  union { u16 h[16]; uint4 q[2]; } pk;
#pragma unroll
  for (int i = 0; i < 16; ++i) {
    float s = 0.f;
#pragma unroll
    for (int c = 0; c < NC; ++c)
      s += P1[(size_t)c * NE * ND + (size_t)(e0 + i) * ND + tid];
    pk.h[i] = f2bf(de[e0 + i] * s);
  }
  uint4* dst = (uint4*)(xhet + (size_t)tid * NE + e0);
  dst[0] = pk.q[0];
  dst[1] = pk.q[1];
}

// ---------------- GEMM2 split-K, counted-vmcnt pipeline.
// grid (96, 8), 512 threads. Block tile 128v x 256d, 8 waves of 64x64.
template <int NC>
__global__ __launch_bounds__(512) void k_gemm2s(
    const float* __restrict__ H, const u16* __restrict__ xhet,
    float* __restrict__ P2) {
  constexpr int KLEN = NE / NC;   // 768
  constexpr int NT = KLEN / 32;   // 24
  __shared__ u16 Alds[2][128 * 40];
  __shared__ u16 Blds[2][256 * 32];
  const int tid = threadIdx.x;
  const int w = tid >> 6, lane = tid & 63, ln = lane & 15, quad = lane >> 4;
  const int wn = w & 3, wm = w >> 2;
  const int m0 = blockIdx.x * 128;
  const int kbase = blockIdx.y * KLEN;
  const int am = tid >> 2, ac = (tid & 3) * 8;   // am 0..127
  f32x4 acc[4][4] = {};
  const float* aH = H + (size_t)(m0 + am) * NE + kbase + ac;

  // ---- prologue: tile 0
  {
    float4 a0 = *(const float4*)(aH);
    float4 a1 = *(const float4*)(aH + 4);
    stage_B8(xhet, NE, kbase, Blds[0]);
    *(short8*)(Alds[0] + am * 40 + ac) = pack8(a0, a1);
    asm volatile("s_waitcnt vmcnt(0) lgkmcnt(0)" ::: "memory");
    __builtin_amdgcn_s_barrier();
    __builtin_amdgcn_sched_barrier(0);
  }
  int cur = 0;
  for (int t = 0; t < NT - 1; ++t) {
    const int nxt = cur ^ 1;
    const float* ap = aH + (t + 1) * 32;
    float4 ma0 = *(const float4*)(ap);
    float4 ma1 = *(const float4*)(ap + 4);
    stage_B8(xhet, NE, kbase + (t + 1) * 32, Blds[nxt]);
    asm volatile("s_waitcnt vmcnt(4) lgkmcnt(0)" ::: "memory");
    __builtin_amdgcn_s_barrier();
    __builtin_amdgcn_sched_barrier(0);
    compute_tile(Alds[cur], wm * 64, Blds[cur], wn * 64, ln, quad, acc);
    __builtin_amdgcn_s_barrier();
    __builtin_amdgcn_sched_barrier(0);
    *(short8*)(Alds[nxt] + am * 40 + ac) = pack8(ma0, ma1);
    cur = nxt;
  }
  // ---- epilogue
  asm volatile("s_waitcnt vmcnt(0) lgkmcnt(0)" ::: "memory");
  __builtin_amdgcn_s_barrier();
  __builtin_amdgcn_sched_barrier(0);
  compute_tile(Alds[cur], wm * 64, Blds[cur], wn * 64, ln, quad, acc);

  float* P = P2 + (size_t)blockIdx.y * NN * ND;
#pragma unroll
  for (int nt = 0; nt < 4; ++nt) {
    const int d = wn * 64 + nt * 16 + ln;
#pragma unroll
    for (int mt = 0; mt < 4; ++mt) {
      const int vb = m0 + wm * 64 + mt * 16 + quad * 4;
      f32x4 a = acc[nt][mt];
#pragma unroll
      for (int r = 0; r < 4; ++r)
        P[(size_t)(vb + r) * ND + d] = a[r];
    }
  }
}

// ---------------- red2: out[v][d] = dv[v] * sum_c P2[c][v][d]
template <int NC>
__global__ __launch_bounds__(256) void k_red2(
    const float* __restrict__ P2, const float* __restrict__ dv,
    float* __restrict__ out) {
  const int tid = threadIdx.x;
  const int v0 = blockIdx.x * 16;
#pragma unroll
  for (int i = 0; i < 16; ++i) {
    float s = 0.f;
#pragma unroll
    for (int c = 0; c < NC; ++c)
      s += P2[(size_t)c * NN * ND + (size_t)(v0 + i) * ND + tid];
    out[(size_t)(v0 + i) * ND + tid] = dv[v0 + i] * s;
  }
}

// ---------------- prep: diag extraction + W transpose to bf16
__global__ __launch_bounds__(256) void k_prep(
    const float* __restrict__ W, const float* __restrict__ Dv,
    const float* __restrict__ De, u16* __restrict__ Wt,
    float* __restrict__ dv, float* __restrict__ de) {
  const int t = blockIdx.x * 256 + threadIdx.x;   // 65536 threads
  const int d = t >> 8, k = t & 255;
  Wt[d * 256 + k] = f2bf(W[k * 256 + d]);
  if (t < NN) dv[t] = Dv[(size_t)t * (NN + 1)];
  if (t < NE) de[t] = De[(size_t)t * (NE + 1)];
}

extern "C" void kernel_launch(void* const* d_in, const int* in_sizes, int n_in,
                              void* d_out, int out_size, void* d_ws, size_t ws_size,
                              hipStream_t stream) {
  const float* x  = (const float*)d_in[0];
  const float* H  = (const float*)d_in[1];
  const float* Dv = (const float*)d_in[2];
  const float* De = (const float*)d_in[3];
  const float* W  = (const float*)d_in[4];
  const float* b  = (const float*)d_in[5];
  float* out = (float*)d_out;
  char* ws = (char*)d_ws;
  u16* xnt   = (u16*)ws;                      // 256 x 12288 bf16 = 6291456 B
  u16* xhet  = (u16*)(ws + 6291456);          // 256 x 6144 bf16  = 3145728 B
  u16* Wt    = (u16*)(ws + 9437184);          // 256 x 256 bf16   = 131072 B
  float* dv  = (float*)(ws + 9568256);        // 12288 f32
  float* de  = (float*)(ws + 9617408);        // 6144 f32
  float* P1  = (float*)(ws + 9641984);        // 100663296 B; P2 aliases P1
  float* P2  = P1;

  hipLaunchKernelGGL(k_prep,       dim3(256), dim3(256), 0, stream, W, Dv, De, Wt, dv, de);
  hipLaunchKernelGGL(k_xform,      dim3(NN / 64), dim3(256), 0, stream, x, Wt, b, dv, xnt);
  hipLaunchKernelGGL(k_gemm1s<16>, dim3(NE / 128, 16), dim3(512), 0, stream, H, xnt, P1);
  hipLaunchKernelGGL(k_red1<16>,   dim3(NE / 16), dim3(256), 0, stream, P1, de, xhet);
  hipLaunchKernelGGL(k_gemm2s<8>,  dim3(NN / 128, 8), dim3(512), 0, stream, H, xhet, P2);
  hipLaunchKernelGGL(k_red2<8>,    dim3(NN / 16), dim3(256), 0, stream, P2, dv, out);
}